// Round 18
// baseline (416.678 us; speedup 1.0000x reference)
//
#include <hip/hip_runtime.h>
#include <hip/hip_fp16.h>

#define LRELU_SLOPE 0.2f
#define BNEPS 1e-5f
#define BK 128        // bucket slots (node>>10; N=100k -> 98 used)
#define TILE 2048     // edges per k_bucket block
#define CAPB 18432    // per-bucket staging capacity (mean 16384 + ~16 sigma)
#define NREPL 256     // pooled replicas (64 KB) for barrier-free pool fusion

__device__ __forceinline__ float lrelu(float x) { return x > 0.f ? x : LRELU_SLOPE * x; }

// ---- fp8 e4m3 (OCP on gfx950) pack/unpack via HW cvt instructions ----------
typedef float v2f __attribute__((ext_vector_type(2)));
__device__ __forceinline__ v2f fp8x4_lo(unsigned int u) {   // bytes 0,1 -> 2 floats
  return __builtin_amdgcn_cvt_pk_f32_fp8((int)u, false);
}
__device__ __forceinline__ v2f fp8x4_hi(unsigned int u) {   // bytes 2,3 -> 2 floats
  return __builtin_amdgcn_cvt_pk_f32_fp8((int)u, true);
}
__device__ __forceinline__ int f32x4_to_fp8x4(float a, float b, float c, float d) {
  int v = __builtin_amdgcn_cvt_pk_fp8_f32(a, b, 0, false);
  v = __builtin_amdgcn_cvt_pk_fp8_f32(c, d, v, true);
  return v;
}
__device__ __forceinline__ unsigned char f32_to_fp8(float a) {
  return (unsigned char)(__builtin_amdgcn_cvt_pk_fp8_f32(a, a, 0, false) & 0xff);
}

// ---------------- bucketed edge sort, pass 1 (cursors are OFFSETS, init=0) ---
__global__ __launch_bounds__(256) void k_bucket(
    const int* __restrict__ src, const int* __restrict__ dst,
    int* __restrict__ cursorOff, int* __restrict__ stg, int E) {
  __shared__ int cnt[BK];
  __shared__ int off[BK];
  __shared__ int base[BK];
  __shared__ int pk[TILE];
  __shared__ int ga[TILE];
  int t = threadIdx.x;
  int tb = blockIdx.x * TILE;

  for (int i = t; i < BK; i += 256) cnt[i] = 0;
  __syncthreads();

  int myp[8], myb[8], myrank[8];
#pragma unroll
  for (int k = 0; k < 8; ++k) {
    int e = tb + k * 256 + t;
    myb[k] = -1;
    if (e < E) {
      int s = src[e], d = dst[e];
      myp[k] = ((d & 1023) << 17) | s;
      myb[k] = d >> 10;
      myrank[k] = atomicAdd(&cnt[myb[k]], 1);
    }
  }
  __syncthreads();
  if (t < BK) off[t] = cnt[t];
  __syncthreads();
  for (int o = 1; o < BK; o <<= 1) {
    int xx = 0;
    if (t < BK && t >= o) xx = off[t - o];
    __syncthreads();
    if (t < BK) off[t] += xx;
    __syncthreads();
  }
  if (t < BK) {
    int c = cnt[t];
    off[t] -= c;                                      // exclusive
    base[t] = t * CAPB + ((c > 0) ? atomicAdd(&cursorOff[t], c) : 0);
  }
  __syncthreads();
#pragma unroll
  for (int k = 0; k < 8; ++k) {
    if (myb[k] >= 0) {
      int p = off[myb[k]] + myrank[k];
      int a = base[myb[k]] + myrank[k];
      int lim = (myb[k] + 1) * CAPB;
      if (a >= lim) a = BK * CAPB + p;   // overflow guard -> dump slot (never read)
      pk[p] = myp[k];
      ga[p] = a;
    }
  }
  __syncthreads();
  int nvalid = min(TILE, E - tb);
#pragma unroll
  for (int k = 0; k < 8; ++k) {
    int p = k * 256 + t;
    if (p < nvalid) stg[ga[p]] = pk[p];
  }
}

// ------- FAT dispatch 2: fine CSR build (98 blocks, 38% of CUs)  ∪  L1 GEMM --
__global__ __launch_bounds__(1024) void k_finegemm(
    const int* __restrict__ stg, const int* __restrict__ cursorOff,
    int* __restrict__ rowbeg, int* __restrict__ rowend, int* __restrict__ csr,
    int N, int NB,
    const float* __restrict__ x, const float* __restrict__ W,   // W1: [64,5]
    const float* __restrict__ asrc, const float* __restrict__ adst,
    unsigned char* __restrict__ hg, float* __restrict__ alsrc, float* __restrict__ aldst) {
  int t = threadIdx.x;
  if (blockIdx.x < NB) {
    // ---- fine body ----
    __shared__ int cnt[1024];
    int b = blockIdx.x;
    int n0 = b << 10;
    int beg = b * CAPB;
    int end = beg + min(cursorOff[b], CAPB);
    cnt[t] = 0;
    __syncthreads();
    for (int j = beg + t; j < end; j += 1024)
      atomicAdd(&cnt[stg[j] >> 17], 1);
    __syncthreads();
    int deg = cnt[t];
    for (int off = 1; off < 1024; off <<= 1) {
      int xx = (t >= off) ? cnt[t - off] : 0;
      __syncthreads();
      cnt[t] += xx;
      __syncthreads();
    }
    int rb = beg + cnt[t] - deg;    // exclusive scan base
    int n = n0 + t;
    if (n < N) { rowbeg[n] = rb; rowend[n] = rb + deg; }
    __syncthreads();
    cnt[t] = rb;                    // becomes cursor
    __syncthreads();
    for (int j = beg + t; j < end; j += 1024) {
      int e = stg[j];
      int pos = atomicAdd(&cnt[e >> 17], 1);
      csr[pos] = e & 0x1FFFF;
    }
  } else {
    // ---- layer-1 GEMM body: 1024 threads = 16 nodes/block ----
    __shared__ float Ws[320];
    for (int i = t; i < 320; i += 1024) Ws[i] = W[i];
    __syncthreads();
    int n = (blockIdx.x - NB) * 16 + (t >> 6);
    int c = t & 63;
    if (n >= N) return;
    float acc = 0.f;
#pragma unroll
    for (int k = 0; k < 5; ++k) acc += x[n * 5 + k] * Ws[c * 5 + k];
    hg[(size_t)n * 64 + c] = f32_to_fp8(acc);
    float ps = acc * asrc[c];
    float pd = acc * adst[c];
#pragma unroll
    for (int off = 1; off < 16; off <<= 1) {
      ps += __shfl_xor(ps, off, 64);
      pd += __shfl_xor(pd, off, 64);
    }
    if ((c & 15) == 0) {
      alsrc[n * 4 + (c >> 4)] = ps;
      aldst[n * 4 + (c >> 4)] = pd;
    }
  }
}

// ---------------- K=64 GEMM (layers 2,3), fp16 input, fp8 h out + logits -----
template <int H>
__global__ __launch_bounds__(256) void k_gemm64(
    const __half* __restrict__ xin, const float* __restrict__ W,  // W: [64,64]
    const float* __restrict__ asrc, const float* __restrict__ adst,
    unsigned char* __restrict__ hg, float* __restrict__ alsrc, float* __restrict__ aldst, int N) {
  __shared__ float Xs[64 * 132];   // [k][n], stride 132 -> b128 conflict-free
  __shared__ float Ws[64 * 65];    // [k][c], stride 65
  int t = threadIdx.x;
  int nb0 = blockIdx.x * 128;

  for (int idx = t; idx < 4096; idx += 256) {
    int c = idx >> 6, k = idx & 63;
    Ws[k * 65 + c] = W[idx];
  }
  {
    int n = t & 127, kh = t >> 7;
    int gn = nb0 + n;
#pragma unroll
    for (int j = 0; j < 4; ++j) {
      int col = kh * 32 + j * 8;
      float f[8];
      if (gn < N) {
        int4 raw = *(const int4*)&xin[(size_t)gn * 64 + col];   // 8 halves, 16B aligned
        const __half2* hp = (const __half2*)&raw;
#pragma unroll
        for (int i = 0; i < 4; ++i) {
          float2 f2 = __half22float2(hp[i]);
          f[i * 2] = f2.x; f[i * 2 + 1] = f2.y;
        }
      } else {
#pragma unroll
        for (int i = 0; i < 8; ++i) f[i] = 0.f;
      }
#pragma unroll
      for (int i = 0; i < 8; ++i) Xs[(col + i) * 132 + n] = f[i];
    }
  }
  __syncthreads();

  int cg = t & 7, ng = t >> 3;
  int c0 = cg * 8;
  float acc[4][8];
#pragma unroll
  for (int i = 0; i < 4; ++i)
#pragma unroll
    for (int j = 0; j < 8; ++j) acc[i][j] = 0.f;

  for (int k = 0; k < 64; ++k) {
    float4 xv = *(const float4*)&Xs[k * 132 + ng * 4];
    float w[8];
#pragma unroll
    for (int j = 0; j < 8; ++j) w[j] = Ws[k * 65 + c0 + j];
#pragma unroll
    for (int j = 0; j < 8; ++j) {
      acc[0][j] += xv.x * w[j];
      acc[1][j] += xv.y * w[j];
      acc[2][j] += xv.z * w[j];
      acc[3][j] += xv.w * w[j];
    }
  }

  float av[8], dv[8];
#pragma unroll
  for (int j = 0; j < 8; ++j) { av[j] = asrc[c0 + j]; dv[j] = adst[c0 + j]; }

#pragma unroll
  for (int i = 0; i < 4; ++i) {
    int n = nb0 + ng * 4 + i;
    float ps = 0.f, pd = 0.f;
#pragma unroll
    for (int j = 0; j < 8; ++j) { ps += acc[i][j] * av[j]; pd += acc[i][j] * dv[j]; }
    ps += __shfl_xor(ps, 1, 64);
    pd += __shfl_xor(pd, 1, 64);
    if (H == 1) {
      ps += __shfl_xor(ps, 2, 64); pd += __shfl_xor(pd, 2, 64);
      ps += __shfl_xor(ps, 4, 64); pd += __shfl_xor(pd, 4, 64);
    }
    if (n < N) {
      int2 pk8;
      pk8.x = f32x4_to_fp8x4(acc[i][0], acc[i][1], acc[i][2], acc[i][3]);
      pk8.y = f32x4_to_fp8x4(acc[i][4], acc[i][5], acc[i][6], acc[i][7]);
      *(int2*)&hg[(size_t)n * 64 + c0] = pk8;   // 8B at 8B-aligned offset
      if (H == 4) {
        if ((cg & 1) == 0) { alsrc[n * 4 + (cg >> 1)] = ps; aldst[n * 4 + (cg >> 1)] = pd; }
      } else {
        if (cg == 0) { alsrc[n] = ps; aldst[n] = pd; }
      }
    }
  }
}

// ---------------- edge-softmax aggregation + bias + BN (+ELU) ----------------
// FROZEN outer structure (one node/wave, 4 nodes/block, guarded chunk-16).
// R18: channel-QUAD lanes — each lane covers 4 channels via one 4B fp8 load
// (cvt_pk hi/lo), the four 16-lane quarters process 4 edges per broadcast
// iteration: per chunk 4 iterations / 4 loads / 8 shfls (was 8/8/16). The
// agg is issue-bound (R17: FETCH -30% but dur -3% at VALUBusy 50%) so fewer
// instructions per edge is the lever. R16 DOPOOL: barrier-free atomic
// epilogue (waves retire independently).
template <int HEADS, bool DOELU, bool DOPOOL>
__global__ __launch_bounds__(256) void k_agg(
    const unsigned char* __restrict__ hg, const float* __restrict__ alsrc, const float* __restrict__ aldst,
    const int* __restrict__ rowbeg, const int* __restrict__ rowend, const int* __restrict__ csr,
    const float* __restrict__ bias, const float* __restrict__ gamma, const float* __restrict__ beta,
    const float* __restrict__ mean, const float* __restrict__ var,
    __half* __restrict__ out, float* __restrict__ pooled, int N) {
  int node = blockIdx.x * 4 + (threadIdx.x >> 6);
  if (node >= N) return;
  int lane = threadIdx.x & 63;
  int e16  = lane & 15;
  int gh   = (HEADS == 4) ? (lane >> 4) : 0;    // gather-role head (p compute)
  int c4   = lane & 15;                          // channel-quad index
  int quar = lane >> 4;                          // 0..3: edge subslot
  int hc   = (HEADS == 4) ? (c4 >> 2) : 0;       // channel-role head
  int psrc = hc * 16;                            // first lane of group hc
  int c0   = 4 * c4;

  float ad = aldst[node * HEADS + gh];
  float pself = __expf(lrelu(alsrc[node * HEADS + gh] + ad));
  float ssum = 0.f;

  float ax, ay, az, aw;
  {
    float pc = __shfl(pself, psrc, 64);
    unsigned int u = *(const unsigned int*)&hg[(size_t)node * 64 + c0];
    v2f lo = fp8x4_lo(u), hi = fp8x4_hi(u);
    bool q0 = (quar == 0);                       // self term once (quarter 0)
    ax = q0 ? pc * lo.x : 0.f;  ay = q0 ? pc * lo.y : 0.f;
    az = q0 ? pc * hi.x : 0.f;  aw = q0 ? pc * hi.y : 0.f;
  }

  int beg = rowbeg[node], end = rowend[node];
  for (int jb = beg; jb < end; jb += 16) {
    int j = jb + e16;
    int s = 0;
    float p = 0.f;
    if (j < end) {
      s = csr[j];
      p = __expf(lrelu(alsrc[s * HEADS + gh] + ad));
    }
    ssum += p;
#pragma unroll
    for (int e = 0; e < 16; e += 4) {
      int eslot = e + quar;                      // quarter q covers slots e+q
      float pj = __shfl(p, psrc + eslot, 64);    // p for my channel-head
      int   sj = __shfl(s, eslot, 64);           // s replicated across groups
      unsigned int u = *(const unsigned int*)&hg[(size_t)sj * 64 + c0];
      v2f lo = fp8x4_lo(u), hi = fp8x4_hi(u);
      ax += pj * lo.x; ay += pj * lo.y;          // OOB slots: p=0 — harmless
      az += pj * hi.x; aw += pj * hi.y;
    }
  }
  ssum += __shfl_xor(ssum, 1, 64);
  ssum += __shfl_xor(ssum, 2, 64);
  ssum += __shfl_xor(ssum, 4, 64);
  ssum += __shfl_xor(ssum, 8, 64);
  float ssum_c = __shfl(ssum, psrc, 64) + __shfl(pself, psrc, 64);

  ax += __shfl_xor(ax, 16, 64); ax += __shfl_xor(ax, 32, 64);
  ay += __shfl_xor(ay, 16, 64); ay += __shfl_xor(ay, 32, 64);
  az += __shfl_xor(az, 16, 64); az += __shfl_xor(az, 32, 64);
  aw += __shfl_xor(aw, 16, 64); aw += __shfl_xor(aw, 32, 64);

  if (quar == 0) {
    float4 bi = *(const float4*)&bias[c0];
    float4 mn = *(const float4*)&mean[c0];
    float4 vr = *(const float4*)&var[c0];
    float4 gm = *(const float4*)&gamma[c0];
    float4 bt = *(const float4*)&beta[c0];
    float inv = 1.f / (ssum_c + 1e-16f);
    float vx = ax * inv + bi.x;
    float vy = ay * inv + bi.y;
    float vz = az * inv + bi.z;
    float vw = aw * inv + bi.w;
    vx = (vx - mn.x) * rsqrtf(vr.x + BNEPS) * gm.x + bt.x;
    vy = (vy - mn.y) * rsqrtf(vr.y + BNEPS) * gm.y + bt.y;
    vz = (vz - mn.z) * rsqrtf(vr.z + BNEPS) * gm.z + bt.z;
    vw = (vw - mn.w) * rsqrtf(vr.w + BNEPS) * gm.w + bt.w;
    if (DOELU) {
      vx = vx > 0.f ? vx : __expf(vx) - 1.f;
      vy = vy > 0.f ? vy : __expf(vy) - 1.f;
      vz = vz > 0.f ? vz : __expf(vz) - 1.f;
      vw = vw > 0.f ? vw : __expf(vw) - 1.f;
    }
    if constexpr (DOPOOL) {
      float* repl = pooled + ((blockIdx.x & (NREPL - 1)) << 6);
      atomicAdd(&repl[c0], vx);
      atomicAdd(&repl[c0 + 1], vy);
      atomicAdd(&repl[c0 + 2], vz);
      atomicAdd(&repl[c0 + 3], vw);
    } else {
      __half2 h01 = __floats2half2_rn(vx, vy);
      __half2 h23 = __floats2half2_rn(vz, vw);
      float2 st;
      *(__half2*)&st.x = h01;
      *(__half2*)&st.y = h23;
      *(float2*)&out[(size_t)node * 64 + c0] = st;   // 8B aligned
    }
  }
}

// ---------------- MLP heads (sums the NREPL pooled replicas) ----------------
__global__ void k_head(const float* __restrict__ pooled,
                       const float* __restrict__ cw1, const float* __restrict__ cb1,
                       const float* __restrict__ cw2, const float* __restrict__ cb2,
                       const float* __restrict__ rw1, const float* __restrict__ rb1,
                       const float* __restrict__ rw2, const float* __restrict__ rb2,
                       float* __restrict__ outp, float invN) {
  __shared__ float ps[64], hc[32], hr[32];
  int t = threadIdx.x;
  float s = 0.f;
#pragma unroll 8
  for (int r = 0; r < NREPL; ++r) s += pooled[r * 64 + t];
  ps[t] = s * invN;
  __syncthreads();
  if (t < 32) {
    float sc = cb1[t], sr = rb1[t];
    for (int c = 0; c < 64; ++c) {
      sc += ps[c] * cw1[t * 64 + c];
      sr += ps[c] * rw1[t * 64 + c];
    }
    hc[t] = sc > 0.f ? sc : 0.f;
    hr[t] = sr > 0.f ? sr : 0.f;
  }
  __syncthreads();
  if (t < 3) {
    float v = cb2[t];
    for (int j = 0; j < 32; ++j) v += hc[j] * cw2[t * 32 + j];
    outp[t] = v;
  } else if (t == 3) {
    float v = rb2[0];
    for (int j = 0; j < 32; ++j) v += hr[j] * rw2[j];
    outp[3] = v;
  }
}

static inline size_t align256(size_t x) { return (x + 255) & ~(size_t)255; }

extern "C" void kernel_launch(void* const* d_in, const int* in_sizes, int n_in,
                              void* d_out, int out_size, void* d_ws, size_t ws_size,
                              hipStream_t stream) {
  const float* x   = (const float*)d_in[0];
  const int*   ei  = (const int*)d_in[1];
  const float* W1  = (const float*)d_in[2];
  const float* a1s = (const float*)d_in[3];
  const float* a1d = (const float*)d_in[4];
  const float* b1  = (const float*)d_in[5];
  const float* W2  = (const float*)d_in[6];
  const float* a2s = (const float*)d_in[7];
  const float* a2d = (const float*)d_in[8];
  const float* b2  = (const float*)d_in[9];
  const float* W3  = (const float*)d_in[10];
  const float* a3s = (const float*)d_in[11];
  const float* a3d = (const float*)d_in[12];
  const float* b3  = (const float*)d_in[13];
  const float* bng = (const float*)d_in[14];
  const float* bnb = (const float*)d_in[15];
  const float* bnm = (const float*)d_in[16];
  const float* bnv = (const float*)d_in[17];
  const float* cw1 = (const float*)d_in[18];
  const float* cb1 = (const float*)d_in[19];
  const float* cw2 = (const float*)d_in[20];
  const float* cb2 = (const float*)d_in[21];
  const float* rw1 = (const float*)d_in[22];
  const float* rb1 = (const float*)d_in[23];
  const float* rw2 = (const float*)d_in[24];
  const float* rb2 = (const float*)d_in[25];

  const int N = in_sizes[0] / 5;
  const int E = in_sizes[1] / 2;
  const int* srcp = ei;
  const int* dstp = ei + E;
  const int NB = (N + 1023) >> 10;

  // workspace carve-up
  char* p = (char*)d_ws;
  int* rowbeg    = (int*)p;  p += align256((size_t)N * 4);
  int* rowend    = (int*)p;  p += align256((size_t)N * 4);
  int* csr       = (int*)p;  p += align256((size_t)BK * CAPB * 4);
  int* cursorOff = (int*)p;                 // BK ints, then pooled right after
  float* pooled  = (float*)(p + BK * 4);    // NREPL replicas x 64 floats
  p += align256(BK * 4 + (size_t)NREPL * 64 * 4);
  unsigned char* hH = (unsigned char*)p; p += align256((size_t)N * 64);  // fp8 gather buf
  __half* hB    = (__half*)p; p += align256((size_t)N * 64 * 2);   // agg out / GEMM in
  float* alsrc  = (float*)p;  p += align256((size_t)N * 4 * 4);
  float* aldst  = (float*)p;  p += align256((size_t)N * 4 * 4);
  int* stg      = (int*)p;    p += align256(((size_t)BK * CAPB + TILE) * 4);
  float* outp   = (float*)d_out;

  const int gNode4 = (N + 3) / 4;
  const int gNode128 = (N + 127) / 128;
  const int nbBucket = (E + TILE - 1) / TILE;
  const int gGemm1 = (N + 15) / 16;

  // one memset covers cursorOff (offsets=0) + pooled (NREPL replicas)
  hipMemsetAsync(cursorOff, 0, BK * 4 + (size_t)NREPL * 64 * 4, stream);
  k_bucket<<<nbBucket, 256, 0, stream>>>(srcp, dstp, cursorOff, stg, E);
  // fused: fine CSR build (98 blocks) + layer-1 GEMM on the idle CUs
  k_finegemm<<<NB + gGemm1, 1024, 0, stream>>>(stg, cursorOff, rowbeg, rowend, csr,
      N, NB, x, W1, a1s, a1d, hH, alsrc, aldst);

  // Layer 1 agg: hH -> hB
  k_agg<4, true, false><<<gNode4, 256, 0, stream>>>(hH, alsrc, aldst, rowbeg, rowend, csr,
      b1, bng + 0, bnb + 0, bnm + 0, bnv + 0, hB, nullptr, N);

  // Layer 2: hB -> hH ; agg -> hB
  k_gemm64<4><<<gNode128, 256, 0, stream>>>(hB, W2, a2s, a2d, hH, alsrc, aldst, N);
  k_agg<4, true, false><<<gNode4, 256, 0, stream>>>(hH, alsrc, aldst, rowbeg, rowend, csr,
      b2, bng + 64, bnb + 64, bnm + 64, bnv + 64, hB, nullptr, N);

  // Layer 3: hB -> hH ; agg (no ELU) with barrier-free fused mean-pool
  k_gemm64<1><<<gNode128, 256, 0, stream>>>(hB, W3, a3s, a3d, hH, alsrc, aldst, N);
  k_agg<1, false, true><<<gNode4, 256, 0, stream>>>(hH, alsrc, aldst, rowbeg, rowend, csr,
      b3, bng + 128, bnb + 128, bnm + 128, bnv + 128, nullptr, pooled, N);

  k_head<<<1, 64, 0, stream>>>(pooled, cw1, cb1, cw2, cb2, rw1, rb1, rw2, rb2,
                               outp, 1.0f / (float)N);
}

// Round 19
// 376.680 us; speedup vs baseline: 1.1062x; 1.1062x over previous
//
#include <hip/hip_runtime.h>
#include <hip/hip_fp16.h>

#define LRELU_SLOPE 0.2f
#define BNEPS 1e-5f
#define BK 128        // bucket slots (node>>10; N=100k -> 98 used)
#define TILE 2048     // edges per k_bucket block
#define CAPB 18432    // per-bucket staging capacity (mean 16384 + ~16 sigma)
#define NREPL 256     // pooled replicas (64 KB) for barrier-free pool fusion

__device__ __forceinline__ float lrelu(float x) { return x > 0.f ? x : LRELU_SLOPE * x; }

// ---- fp8 e4m3 (OCP on gfx950) pack/unpack via HW cvt instructions ----------
typedef float v2f __attribute__((ext_vector_type(2)));
__device__ __forceinline__ v2f fp8x2_to_f32x2(unsigned short u) {
  return __builtin_amdgcn_cvt_pk_f32_fp8((int)u, false);
}
__device__ __forceinline__ int f32x4_to_fp8x4(float a, float b, float c, float d) {
  int v = __builtin_amdgcn_cvt_pk_fp8_f32(a, b, 0, false);
  v = __builtin_amdgcn_cvt_pk_fp8_f32(c, d, v, true);
  return v;
}
__device__ __forceinline__ unsigned char f32_to_fp8(float a) {
  return (unsigned char)(__builtin_amdgcn_cvt_pk_fp8_f32(a, a, 0, false) & 0xff);
}

// ---------------- bucketed edge sort, pass 1 (cursors are OFFSETS, init=0) ---
__global__ __launch_bounds__(256) void k_bucket(
    const int* __restrict__ src, const int* __restrict__ dst,
    int* __restrict__ cursorOff, int* __restrict__ stg, int E) {
  __shared__ int cnt[BK];
  __shared__ int off[BK];
  __shared__ int base[BK];
  __shared__ int pk[TILE];
  __shared__ int ga[TILE];
  int t = threadIdx.x;
  int tb = blockIdx.x * TILE;

  for (int i = t; i < BK; i += 256) cnt[i] = 0;
  __syncthreads();

  int myp[8], myb[8], myrank[8];
#pragma unroll
  for (int k = 0; k < 8; ++k) {
    int e = tb + k * 256 + t;
    myb[k] = -1;
    if (e < E) {
      int s = src[e], d = dst[e];
      myp[k] = ((d & 1023) << 17) | s;
      myb[k] = d >> 10;
      myrank[k] = atomicAdd(&cnt[myb[k]], 1);
    }
  }
  __syncthreads();
  if (t < BK) off[t] = cnt[t];
  __syncthreads();
  for (int o = 1; o < BK; o <<= 1) {
    int xx = 0;
    if (t < BK && t >= o) xx = off[t - o];
    __syncthreads();
    if (t < BK) off[t] += xx;
    __syncthreads();
  }
  if (t < BK) {
    int c = cnt[t];
    off[t] -= c;                                      // exclusive
    base[t] = t * CAPB + ((c > 0) ? atomicAdd(&cursorOff[t], c) : 0);
  }
  __syncthreads();
#pragma unroll
  for (int k = 0; k < 8; ++k) {
    if (myb[k] >= 0) {
      int p = off[myb[k]] + myrank[k];
      int a = base[myb[k]] + myrank[k];
      int lim = (myb[k] + 1) * CAPB;
      if (a >= lim) a = BK * CAPB + p;   // overflow guard -> dump slot (never read)
      pk[p] = myp[k];
      ga[p] = a;
    }
  }
  __syncthreads();
  int nvalid = min(TILE, E - tb);
#pragma unroll
  for (int k = 0; k < 8; ++k) {
    int p = k * 256 + t;
    if (p < nvalid) stg[ga[p]] = pk[p];
  }
}

// ------- FAT dispatch 2: fine CSR build (98 blocks, 38% of CUs)  ∪  L1 GEMM --
__global__ __launch_bounds__(1024) void k_finegemm(
    const int* __restrict__ stg, const int* __restrict__ cursorOff,
    int* __restrict__ rowbeg, int* __restrict__ rowend, int* __restrict__ csr,
    int N, int NB,
    const float* __restrict__ x, const float* __restrict__ W,   // W1: [64,5]
    const float* __restrict__ asrc, const float* __restrict__ adst,
    unsigned char* __restrict__ hg, float* __restrict__ alsrc, float* __restrict__ aldst) {
  int t = threadIdx.x;
  if (blockIdx.x < NB) {
    // ---- fine body ----
    __shared__ int cnt[1024];
    int b = blockIdx.x;
    int n0 = b << 10;
    int beg = b * CAPB;
    int end = beg + min(cursorOff[b], CAPB);
    cnt[t] = 0;
    __syncthreads();
    for (int j = beg + t; j < end; j += 1024)
      atomicAdd(&cnt[stg[j] >> 17], 1);
    __syncthreads();
    int deg = cnt[t];
    for (int off = 1; off < 1024; off <<= 1) {
      int xx = (t >= off) ? cnt[t - off] : 0;
      __syncthreads();
      cnt[t] += xx;
      __syncthreads();
    }
    int rb = beg + cnt[t] - deg;    // exclusive scan base
    int n = n0 + t;
    if (n < N) { rowbeg[n] = rb; rowend[n] = rb + deg; }
    __syncthreads();
    cnt[t] = rb;                    // becomes cursor
    __syncthreads();
    for (int j = beg + t; j < end; j += 1024) {
      int e = stg[j];
      int pos = atomicAdd(&cnt[e >> 17], 1);
      csr[pos] = e & 0x1FFFF;
    }
  } else {
    // ---- layer-1 GEMM body: 1024 threads = 16 nodes/block ----
    __shared__ float Ws[320];
    for (int i = t; i < 320; i += 1024) Ws[i] = W[i];
    __syncthreads();
    int n = (blockIdx.x - NB) * 16 + (t >> 6);
    int c = t & 63;
    if (n >= N) return;
    float acc = 0.f;
#pragma unroll
    for (int k = 0; k < 5; ++k) acc += x[n * 5 + k] * Ws[c * 5 + k];
    hg[(size_t)n * 64 + c] = f32_to_fp8(acc);
    float ps = acc * asrc[c];
    float pd = acc * adst[c];
#pragma unroll
    for (int off = 1; off < 16; off <<= 1) {
      ps += __shfl_xor(ps, off, 64);
      pd += __shfl_xor(pd, off, 64);
    }
    if ((c & 15) == 0) {
      alsrc[n * 4 + (c >> 4)] = ps;
      aldst[n * 4 + (c >> 4)] = pd;
    }
  }
}

// ---------------- K=64 GEMM (layers 2,3), fp16 input, fp8 h out + logits -----
template <int H>
__global__ __launch_bounds__(256) void k_gemm64(
    const __half* __restrict__ xin, const float* __restrict__ W,  // W: [64,64]
    const float* __restrict__ asrc, const float* __restrict__ adst,
    unsigned char* __restrict__ hg, float* __restrict__ alsrc, float* __restrict__ aldst, int N) {
  __shared__ float Xs[64 * 132];   // [k][n], stride 132 -> b128 conflict-free
  __shared__ float Ws[64 * 65];    // [k][c], stride 65
  int t = threadIdx.x;
  int nb0 = blockIdx.x * 128;

  for (int idx = t; idx < 4096; idx += 256) {
    int c = idx >> 6, k = idx & 63;
    Ws[k * 65 + c] = W[idx];
  }
  {
    int n = t & 127, kh = t >> 7;
    int gn = nb0 + n;
#pragma unroll
    for (int j = 0; j < 4; ++j) {
      int col = kh * 32 + j * 8;
      float f[8];
      if (gn < N) {
        int4 raw = *(const int4*)&xin[(size_t)gn * 64 + col];   // 8 halves, 16B aligned
        const __half2* hp = (const __half2*)&raw;
#pragma unroll
        for (int i = 0; i < 4; ++i) {
          float2 f2 = __half22float2(hp[i]);
          f[i * 2] = f2.x; f[i * 2 + 1] = f2.y;
        }
      } else {
#pragma unroll
        for (int i = 0; i < 8; ++i) f[i] = 0.f;
      }
#pragma unroll
      for (int i = 0; i < 8; ++i) Xs[(col + i) * 132 + n] = f[i];
    }
  }
  __syncthreads();

  int cg = t & 7, ng = t >> 3;
  int c0 = cg * 8;
  float acc[4][8];
#pragma unroll
  for (int i = 0; i < 4; ++i)
#pragma unroll
    for (int j = 0; j < 8; ++j) acc[i][j] = 0.f;

  for (int k = 0; k < 64; ++k) {
    float4 xv = *(const float4*)&Xs[k * 132 + ng * 4];
    float w[8];
#pragma unroll
    for (int j = 0; j < 8; ++j) w[j] = Ws[k * 65 + c0 + j];
#pragma unroll
    for (int j = 0; j < 8; ++j) {
      acc[0][j] += xv.x * w[j];
      acc[1][j] += xv.y * w[j];
      acc[2][j] += xv.z * w[j];
      acc[3][j] += xv.w * w[j];
    }
  }

  float av[8], dv[8];
#pragma unroll
  for (int j = 0; j < 8; ++j) { av[j] = asrc[c0 + j]; dv[j] = adst[c0 + j]; }

#pragma unroll
  for (int i = 0; i < 4; ++i) {
    int n = nb0 + ng * 4 + i;
    float ps = 0.f, pd = 0.f;
#pragma unroll
    for (int j = 0; j < 8; ++j) { ps += acc[i][j] * av[j]; pd += acc[i][j] * dv[j]; }
    ps += __shfl_xor(ps, 1, 64);
    pd += __shfl_xor(pd, 1, 64);
    if (H == 1) {
      ps += __shfl_xor(ps, 2, 64); pd += __shfl_xor(pd, 2, 64);
      ps += __shfl_xor(ps, 4, 64); pd += __shfl_xor(pd, 4, 64);
    }
    if (n < N) {
      int2 pk8;
      pk8.x = f32x4_to_fp8x4(acc[i][0], acc[i][1], acc[i][2], acc[i][3]);
      pk8.y = f32x4_to_fp8x4(acc[i][4], acc[i][5], acc[i][6], acc[i][7]);
      *(int2*)&hg[(size_t)n * 64 + c0] = pk8;   // 8B at 8B-aligned offset
      if (H == 4) {
        if ((cg & 1) == 0) { alsrc[n * 4 + (cg >> 1)] = ps; aldst[n * 4 + (cg >> 1)] = pd; }
      } else {
        if (cg == 0) { alsrc[n] = ps; aldst[n] = pd; }
      }
    }
  }
}

// ---------------- edge-softmax aggregation + bias + BN (+ELU) ----------------
// R17 channel-PAIR loop (measured fastest; R18's channel-quad was neutral on
// the loop and doubled atomic line-RMWs in the epilogue -> reverted). R19
// DOPOOL epilogue: BN computed on ALL 64 lanes (both halves hold the reduced
// acc after the xor-32 combine), then ONE atomic instruction per wave — lane
// i adds component (lane>>5) to channel 2*(lane&31)+(lane>>5). 64 atomics in
// 1 instruction x 4 lines = 4 line-RMWs/node (R16 pair epilogue: 8; R18
// quad: 16 -> 92us).
template <int HEADS, bool DOELU, bool DOPOOL>
__global__ __launch_bounds__(256) void k_agg(
    const unsigned char* __restrict__ hg, const float* __restrict__ alsrc, const float* __restrict__ aldst,
    const int* __restrict__ rowbeg, const int* __restrict__ rowend, const int* __restrict__ csr,
    const float* __restrict__ bias, const float* __restrict__ gamma, const float* __restrict__ beta,
    const float* __restrict__ mean, const float* __restrict__ var,
    __half* __restrict__ out, float* __restrict__ pooled, int N) {
  int node = blockIdx.x * 4 + (threadIdx.x >> 6);
  if (node >= N) return;
  int lane = threadIdx.x & 63;
  int e16  = lane & 15;
  int gh   = (HEADS == 4) ? (lane >> 4) : 0;    // gather-role head
  int c2   = lane & 31;                          // channel-pair index
  int half = lane >> 5;                          // 0/1: which edge of the pair
  int hc   = (HEADS == 4) ? (c2 >> 3) : 0;       // channel-role head
  int psrc = hc * 16;                            // first lane of group hc
  int c0   = 2 * c2;

  float ad = aldst[node * HEADS + gh];
  float pself = __expf(lrelu(alsrc[node * HEADS + gh] + ad));
  float ssum = 0.f;

  float accx, accy;
  {
    float pc = __shfl(pself, psrc, 64);
    v2f hf = fp8x2_to_f32x2(*(const unsigned short*)&hg[(size_t)node * 64 + c0]);
    // self term only in half 0 (cross-half combine would double it)
    accx = (half == 0) ? pc * hf.x : 0.f;
    accy = (half == 0) ? pc * hf.y : 0.f;
  }

  int beg = rowbeg[node], end = rowend[node];
  for (int jb = beg; jb < end; jb += 16) {
    int j = jb + e16;
    int s = 0;
    float p = 0.f;
    if (j < end) {
      s = csr[j];
      p = __expf(lrelu(alsrc[s * HEADS + gh] + ad));
    }
    ssum += p;
#pragma unroll
    for (int e = 0; e < 16; e += 2) {
      int eslot = e + half;                       // half0: even slots, half1: odd
      float pj = __shfl(p, psrc + eslot, 64);     // p for my channel-head
      int   sj = __shfl(s, eslot, 64);            // s replicated across groups
      v2f hf = fp8x2_to_f32x2(*(const unsigned short*)&hg[(size_t)sj * 64 + c0]);
      accx += pj * hf.x;                          // OOB slots: p=0 — harmless
      accy += pj * hf.y;
    }
  }
  ssum += __shfl_xor(ssum, 1, 64);
  ssum += __shfl_xor(ssum, 2, 64);
  ssum += __shfl_xor(ssum, 4, 64);
  ssum += __shfl_xor(ssum, 8, 64);
  float ssum_c = __shfl(ssum, psrc, 64) + __shfl(pself, psrc, 64);

  accx += __shfl_xor(accx, 32, 64);   // both halves now hold the full sums
  accy += __shfl_xor(accy, 32, 64);

  if constexpr (DOPOOL) {
    // BN on all 64 lanes (redundant across halves, but enables the 1-instr
    // atomic epilogue); ssum_c is valid on both halves (psrc is half-agnostic).
    float2 bi = *(const float2*)&bias[c0];
    float2 mn = *(const float2*)&mean[c0];
    float2 vr = *(const float2*)&var[c0];
    float2 gm = *(const float2*)&gamma[c0];
    float2 bt = *(const float2*)&beta[c0];
    float inv = 1.f / (ssum_c + 1e-16f);
    float vx = accx * inv + bi.x;
    float vy = accy * inv + bi.y;
    vx = (vx - mn.x) * rsqrtf(vr.x + BNEPS) * gm.x + bt.x;
    vy = (vy - mn.y) * rsqrtf(vr.y + BNEPS) * gm.y + bt.y;
    if (DOELU) {
      vx = vx > 0.f ? vx : __expf(vx) - 1.f;
      vy = vy > 0.f ? vy : __expf(vy) - 1.f;
    }
    float val = (half == 0) ? vx : vy;            // lane's component
    float* repl = pooled + ((blockIdx.x & (NREPL - 1)) << 6);
    atomicAdd(&repl[c0 + half], val);             // ONE instruction, 64 lanes
  } else {
    if (half == 0) {
      float2 bi = *(const float2*)&bias[c0];
      float2 mn = *(const float2*)&mean[c0];
      float2 vr = *(const float2*)&var[c0];
      float2 gm = *(const float2*)&gamma[c0];
      float2 bt = *(const float2*)&beta[c0];
      float inv = 1.f / (ssum_c + 1e-16f);
      float vx = accx * inv + bi.x;
      float vy = accy * inv + bi.y;
      vx = (vx - mn.x) * rsqrtf(vr.x + BNEPS) * gm.x + bt.x;
      vy = (vy - mn.y) * rsqrtf(vr.y + BNEPS) * gm.y + bt.y;
      if (DOELU) {
        vx = vx > 0.f ? vx : __expf(vx) - 1.f;
        vy = vy > 0.f ? vy : __expf(vy) - 1.f;
      }
      *(__half2*)&out[(size_t)node * 64 + c0] = __floats2half2_rn(vx, vy);
    }
  }
}

// ---------------- MLP heads (sums the NREPL pooled replicas) ----------------
__global__ void k_head(const float* __restrict__ pooled,
                       const float* __restrict__ cw1, const float* __restrict__ cb1,
                       const float* __restrict__ cw2, const float* __restrict__ cb2,
                       const float* __restrict__ rw1, const float* __restrict__ rb1,
                       const float* __restrict__ rw2, const float* __restrict__ rb2,
                       float* __restrict__ outp, float invN) {
  __shared__ float ps[64], hc[32], hr[32];
  int t = threadIdx.x;
  float s = 0.f;
#pragma unroll 8
  for (int r = 0; r < NREPL; ++r) s += pooled[r * 64 + t];
  ps[t] = s * invN;
  __syncthreads();
  if (t < 32) {
    float sc = cb1[t], sr = rb1[t];
    for (int c = 0; c < 64; ++c) {
      sc += ps[c] * cw1[t * 64 + c];
      sr += ps[c] * rw1[t * 64 + c];
    }
    hc[t] = sc > 0.f ? sc : 0.f;
    hr[t] = sr > 0.f ? sr : 0.f;
  }
  __syncthreads();
  if (t < 3) {
    float v = cb2[t];
    for (int j = 0; j < 32; ++j) v += hc[j] * cw2[t * 32 + j];
    outp[t] = v;
  } else if (t == 3) {
    float v = rb2[0];
    for (int j = 0; j < 32; ++j) v += hr[j] * rw2[j];
    outp[3] = v;
  }
}

static inline size_t align256(size_t x) { return (x + 255) & ~(size_t)255; }

extern "C" void kernel_launch(void* const* d_in, const int* in_sizes, int n_in,
                              void* d_out, int out_size, void* d_ws, size_t ws_size,
                              hipStream_t stream) {
  const float* x   = (const float*)d_in[0];
  const int*   ei  = (const int*)d_in[1];
  const float* W1  = (const float*)d_in[2];
  const float* a1s = (const float*)d_in[3];
  const float* a1d = (const float*)d_in[4];
  const float* b1  = (const float*)d_in[5];
  const float* W2  = (const float*)d_in[6];
  const float* a2s = (const float*)d_in[7];
  const float* a2d = (const float*)d_in[8];
  const float* b2  = (const float*)d_in[9];
  const float* W3  = (const float*)d_in[10];
  const float* a3s = (const float*)d_in[11];
  const float* a3d = (const float*)d_in[12];
  const float* b3  = (const float*)d_in[13];
  const float* bng = (const float*)d_in[14];
  const float* bnb = (const float*)d_in[15];
  const float* bnm = (const float*)d_in[16];
  const float* bnv = (const float*)d_in[17];
  const float* cw1 = (const float*)d_in[18];
  const float* cb1 = (const float*)d_in[19];
  const float* cw2 = (const float*)d_in[20];
  const float* cb2 = (const float*)d_in[21];
  const float* rw1 = (const float*)d_in[22];
  const float* rb1 = (const float*)d_in[23];
  const float* rw2 = (const float*)d_in[24];
  const float* rb2 = (const float*)d_in[25];

  const int N = in_sizes[0] / 5;
  const int E = in_sizes[1] / 2;
  const int* srcp = ei;
  const int* dstp = ei + E;
  const int NB = (N + 1023) >> 10;

  // workspace carve-up
  char* p = (char*)d_ws;
  int* rowbeg    = (int*)p;  p += align256((size_t)N * 4);
  int* rowend    = (int*)p;  p += align256((size_t)N * 4);
  int* csr       = (int*)p;  p += align256((size_t)BK * CAPB * 4);
  int* cursorOff = (int*)p;                 // BK ints, then pooled right after
  float* pooled  = (float*)(p + BK * 4);    // NREPL replicas x 64 floats
  p += align256(BK * 4 + (size_t)NREPL * 64 * 4);
  unsigned char* hH = (unsigned char*)p; p += align256((size_t)N * 64);  // fp8 gather buf
  __half* hB    = (__half*)p; p += align256((size_t)N * 64 * 2);   // agg out / GEMM in
  float* alsrc  = (float*)p;  p += align256((size_t)N * 4 * 4);
  float* aldst  = (float*)p;  p += align256((size_t)N * 4 * 4);
  int* stg      = (int*)p;    p += align256(((size_t)BK * CAPB + TILE) * 4);
  float* outp   = (float*)d_out;

  const int gNode4 = (N + 3) / 4;
  const int gNode128 = (N + 127) / 128;
  const int nbBucket = (E + TILE - 1) / TILE;
  const int gGemm1 = (N + 15) / 16;

  // one memset covers cursorOff (offsets=0) + pooled (NREPL replicas)
  hipMemsetAsync(cursorOff, 0, BK * 4 + (size_t)NREPL * 64 * 4, stream);
  k_bucket<<<nbBucket, 256, 0, stream>>>(srcp, dstp, cursorOff, stg, E);
  // fused: fine CSR build (98 blocks) + layer-1 GEMM on the idle CUs
  k_finegemm<<<NB + gGemm1, 1024, 0, stream>>>(stg, cursorOff, rowbeg, rowend, csr,
      N, NB, x, W1, a1s, a1d, hH, alsrc, aldst);

  // Layer 1 agg: hH -> hB
  k_agg<4, true, false><<<gNode4, 256, 0, stream>>>(hH, alsrc, aldst, rowbeg, rowend, csr,
      b1, bng + 0, bnb + 0, bnm + 0, bnv + 0, hB, nullptr, N);

  // Layer 2: hB -> hH ; agg -> hB
  k_gemm64<4><<<gNode128, 256, 0, stream>>>(hB, W2, a2s, a2d, hH, alsrc, aldst, N);
  k_agg<4, true, false><<<gNode4, 256, 0, stream>>>(hH, alsrc, aldst, rowbeg, rowend, csr,
      b2, bng + 64, bnb + 64, bnm + 64, bnv + 64, hB, nullptr, N);

  // Layer 3: hB -> hH ; agg (no ELU) with barrier-free fused mean-pool
  k_gemm64<1><<<gNode128, 256, 0, stream>>>(hB, W3, a3s, a3d, hH, alsrc, aldst, N);
  k_agg<1, false, true><<<gNode4, 256, 0, stream>>>(hH, alsrc, aldst, rowbeg, rowend, csr,
      b3, bng + 128, bnb + 128, bnm + 128, bnv + 128, nullptr, pooled, N);

  k_head<<<1, 64, 0, stream>>>(pooled, cw1, cb1, cw2, cb2, rw1, rb1, rw2, rb2,
                               outp, 1.0f / (float)N);
}